// Round 1
// baseline (23469.034 us; speedup 1.0000x reference)
//
#include <hip/hip_runtime.h>
#include <math.h>

// ---------------------------------------------------------------------------
// RED regularization: 48-step recurrent U-Net, fp32 direct convs.
// Levels: L0 256x320, L1 128x160, L2 64x80, L3 32x40. BC=8.
// Per step: conv1(s2,8->16) conv2(s2,16->32) conv3(s2,32->64)
//           gru4(128) up3(64->32) gru3(64) up2(32->16) gru2(32)
//           up1(16->8) gru1(16) out(8->1)
// ---------------------------------------------------------------------------

namespace {

constexpr int H0 = 256, W0 = 320, H1 = 128, W1 = 160, H2 = 64, W2 = 80, H3 = 32, W3 = 40;
constexpr int HW0 = H0 * W0, HW1 = H1 * W1, HW2 = H2 * W2, HW3 = H3 * W3;
constexpr int DEPTH = 48;

// ---------------- stride-2 3x3 conv, pad 1, + ReLU -------------------------
// Each block: output tile TX x TY, stages (2TY+1)x(2TX+1)xCIN input in LDS.
// Thread = one output pixel, OCPT output channels per loop iteration.
template <int CIN, int COUT, int TX, int TY, int OCPT, bool NEG>
__global__ __launch_bounds__(256) void conv_s2_k(
    const float* __restrict__ in, int cstr, int inH, int inW,
    const float* __restrict__ w, const float* __restrict__ bias,
    float* __restrict__ out, int outH, int outW) {
  constexpr int IH = 2 * TY + 1, IW = 2 * TX + 1;
  __shared__ float lds[CIN * IH * IW];
  const int x0 = blockIdx.x * TX, y0 = blockIdx.y * TY;
  const int ix0 = 2 * x0 - 1, iy0 = 2 * y0 - 1;
  for (int idx = threadIdx.x; idx < CIN * IH * IW; idx += 256) {
    int c = idx / (IH * IW), r = idx % (IH * IW);
    int yy = r / IW, xx = r % IW;
    int gy = iy0 + yy, gx = ix0 + xx;
    float v = 0.f;
    if ((unsigned)gy < (unsigned)inH && (unsigned)gx < (unsigned)inW)
      v = in[c * cstr + gy * inW + gx];
    lds[(c * IH + yy) * IW + xx] = NEG ? -v : v;
  }
  __syncthreads();
  constexpr int NPX = TX * TY, SUBS = 256 / NPX, NOCG = COUT / OCPT;
  const int px = threadIdx.x % NPX, sub = threadIdx.x / NPX;
  const int tx = px % TX, ty = px / TX;
  const int ox = x0 + tx, oy = y0 + ty;
  const int gPer = NOCG / gridDim.z, g0 = blockIdx.z * gPer;
  for (int g = g0 + sub; g < g0 + gPer; g += SUBS) {
    const int gu = __builtin_amdgcn_readfirstlane(g);  // wave-uniform (NPX % 64 == 0)
    float acc[OCPT];
#pragma unroll
    for (int j = 0; j < OCPT; j++) acc[j] = bias[gu * OCPT + j];
    const float* wg = w + (size_t)gu * OCPT * CIN * 9;
    for (int c = 0; c < CIN; c++) {
      float v[9];
#pragma unroll
      for (int ky = 0; ky < 3; ky++)
#pragma unroll
        for (int kx = 0; kx < 3; kx++)
          v[ky * 3 + kx] = lds[(c * IH + 2 * ty + ky) * IW + 2 * tx + kx];
      const float* wc = wg + c * 9;
#pragma unroll
      for (int j = 0; j < OCPT; j++)
#pragma unroll
        for (int k = 0; k < 9; k++)
          acc[j] = fmaf(v[k], wc[j * CIN * 9 + k], acc[j]);
    }
    if (ox < outW && oy < outH) {
#pragma unroll
      for (int j = 0; j < OCPT; j++)
        out[((gu * OCPT + j) * outH + oy) * outW + ox] = fmaxf(acc[j], 0.f);
    }
  }
}

// ---------------- GRU gate conv: sigmoid(conv(concat(x,h))) ----------------
template <int CX, int CH, int TX, int TY, int OCPT, bool NEGX>
__global__ __launch_bounds__(256) void conv_gate_k(
    const float* __restrict__ x, int xcs, const float* __restrict__ h,
    int H, int W, const float* __restrict__ w, const float* __restrict__ bias,
    float* __restrict__ gates) {
  constexpr int CIN = CX + CH, COUT = 2 * CH, IH = TY + 2, IW = TX + 2;
  __shared__ float lds[CIN * IH * IW];
  const int x0 = blockIdx.x * TX, y0 = blockIdx.y * TY;
  const int HW = H * W;
  for (int idx = threadIdx.x; idx < CIN * IH * IW; idx += 256) {
    int c = idx / (IH * IW), r = idx % (IH * IW);
    int yy = r / IW, xx = r % IW;
    int gy = y0 + yy - 1, gx = x0 + xx - 1;
    float v = 0.f;
    if ((unsigned)gy < (unsigned)H && (unsigned)gx < (unsigned)W) {
      if (c < CX) {
        v = x[c * xcs + gy * W + gx];
        if (NEGX) v = -v;
      } else {
        v = h[(c - CX) * HW + gy * W + gx];
      }
    }
    lds[(c * IH + yy) * IW + xx] = v;
  }
  __syncthreads();
  constexpr int NPX = TX * TY, SUBS = 256 / NPX, NOCG = COUT / OCPT;
  const int px = threadIdx.x % NPX, sub = threadIdx.x / NPX;
  const int tx = px % TX, ty = px / TX;
  const int ox = x0 + tx, oy = y0 + ty;
  const int gPer = NOCG / gridDim.z, g0 = blockIdx.z * gPer;
  for (int g = g0 + sub; g < g0 + gPer; g += SUBS) {
    const int gu = __builtin_amdgcn_readfirstlane(g);
    float acc[OCPT];
#pragma unroll
    for (int j = 0; j < OCPT; j++) acc[j] = bias[gu * OCPT + j];
    const float* wg = w + (size_t)gu * OCPT * CIN * 9;
    for (int c = 0; c < CIN; c++) {
      float v[9];
#pragma unroll
      for (int ky = 0; ky < 3; ky++)
#pragma unroll
        for (int kx = 0; kx < 3; kx++)
          v[ky * 3 + kx] = lds[(c * IH + ty + ky) * IW + tx + kx];
      const float* wc = wg + c * 9;
#pragma unroll
      for (int j = 0; j < OCPT; j++)
#pragma unroll
        for (int k = 0; k < 9; k++)
          acc[j] = fmaf(v[k], wc[j * CIN * 9 + k], acc[j]);
    }
    if (ox < W && oy < H) {
#pragma unroll
      for (int j = 0; j < OCPT; j++)
        gates[(gu * OCPT + j) * HW + oy * W + ox] = 1.f / (1.f + expf(-acc[j]));
    }
  }
}

// -------- GRU cand conv: tanh(conv(concat(x, r*h))) + convex combine -------
template <int CX, int CH, int TX, int TY, int OCPT, bool NEGX>
__global__ __launch_bounds__(256) void conv_cand_k(
    const float* __restrict__ x, int xcs, const float* __restrict__ h,
    const float* __restrict__ gates, int H, int W,
    const float* __restrict__ w, const float* __restrict__ bias,
    float* __restrict__ hout) {
  constexpr int CIN = CX + CH, COUT = CH, IH = TY + 2, IW = TX + 2;
  __shared__ float lds[CIN * IH * IW];
  const int x0 = blockIdx.x * TX, y0 = blockIdx.y * TY;
  const int HW = H * W;
  for (int idx = threadIdx.x; idx < CIN * IH * IW; idx += 256) {
    int c = idx / (IH * IW), r = idx % (IH * IW);
    int yy = r / IW, xx = r % IW;
    int gy = y0 + yy - 1, gx = x0 + xx - 1;
    float v = 0.f;
    if ((unsigned)gy < (unsigned)H && (unsigned)gx < (unsigned)W) {
      if (c < CX) {
        v = x[c * xcs + gy * W + gx];
        if (NEGX) v = -v;
      } else {
        int p = (c - CX) * HW + gy * W + gx;
        v = gates[p] * h[p];  // r (gate ch 0..CH-1) * h
      }
    }
    lds[(c * IH + yy) * IW + xx] = v;
  }
  __syncthreads();
  constexpr int NPX = TX * TY, SUBS = 256 / NPX, NOCG = COUT / OCPT;
  const int px = threadIdx.x % NPX, sub = threadIdx.x / NPX;
  const int tx = px % TX, ty = px / TX;
  const int ox = x0 + tx, oy = y0 + ty;
  const int gPer = NOCG / gridDim.z, g0 = blockIdx.z * gPer;
  for (int g = g0 + sub; g < g0 + gPer; g += SUBS) {
    const int gu = __builtin_amdgcn_readfirstlane(g);
    float acc[OCPT];
#pragma unroll
    for (int j = 0; j < OCPT; j++) acc[j] = bias[gu * OCPT + j];
    const float* wg = w + (size_t)gu * OCPT * CIN * 9;
    for (int c = 0; c < CIN; c++) {
      float v[9];
#pragma unroll
      for (int ky = 0; ky < 3; ky++)
#pragma unroll
        for (int kx = 0; kx < 3; kx++)
          v[ky * 3 + kx] = lds[(c * IH + ty + ky) * IW + tx + kx];
      const float* wc = wg + c * 9;
#pragma unroll
      for (int j = 0; j < OCPT; j++)
#pragma unroll
        for (int k = 0; k < 9; k++)
          acc[j] = fmaf(v[k], wc[j * CIN * 9 + k], acc[j]);
    }
    if (ox < W && oy < H) {
      const int opix = oy * W + ox;
#pragma unroll
      for (int j = 0; j < OCPT; j++) {
        const int oc = gu * OCPT + j;
        float cd = tanhf(acc[j]);
        float u = gates[(CH + oc) * HW + opix];  // update gate (second half)
        float hv = h[oc * HW + opix];
        hout[oc * HW + opix] = u * hv + (1.f - u) * cd;
      }
    }
  }
}

// ------- ConvTranspose 3x3 s2 p1 op1 (input-dilated conv) + ReLU -----------
// Thread computes a 2x2 output quad from a 2x2 input patch (parity-exact taps,
// no divergence, no zero-stuffed work). Optional elementwise sum of 2 inputs.
template <int CIN, int COUT, int TX, int TY, int OCPT, bool SUM2>
__global__ __launch_bounds__(256) void convT_k(
    const float* __restrict__ inA, const float* __restrict__ inB,
    int inH, int inW, const float* __restrict__ w,
    const float* __restrict__ bias, float* __restrict__ out) {
  constexpr int IH = TY / 2 + 1, IW = TX / 2 + 1;
  __shared__ float lds[CIN * IH * IW];
  const int x0 = blockIdx.x * TX, y0 = blockIdx.y * TY;  // output tile origin (even)
  const int ix0 = x0 / 2, iy0 = y0 / 2;
  const int HWin = inH * inW;
  for (int idx = threadIdx.x; idx < CIN * IH * IW; idx += 256) {
    int c = idx / (IH * IW), r = idx % (IH * IW);
    int yy = r / IW, xx = r % IW;
    int gy = iy0 + yy, gx = ix0 + xx;
    float v = 0.f;
    if (gy < inH && gx < inW) {
      v = inA[c * HWin + gy * inW + gx];
      if (SUM2) v += inB[c * HWin + gy * inW + gx];
    }
    lds[(c * IH + yy) * IW + xx] = v;
  }
  __syncthreads();
  constexpr int QX = TX / 2, QY = TY / 2, NPX = QX * QY;
  constexpr int SUBS = 256 / NPX, NOCG = COUT / OCPT;
  const int q = threadIdx.x % NPX, sub = threadIdx.x / NPX;
  const int qx = q % QX, qy = q / QX;
  const int outW = 2 * inW;
  const int oy = y0 + 2 * qy, ox = x0 + 2 * qx;
  const int gPer = NOCG / gridDim.z, g0 = blockIdx.z * gPer;
  for (int g = g0 + sub; g < g0 + gPer; g += SUBS) {
    const int gu = __builtin_amdgcn_readfirstlane(g);
    float a00[OCPT], a01[OCPT], a10[OCPT], a11[OCPT];
#pragma unroll
    for (int j = 0; j < OCPT; j++) {
      float bb = bias[gu * OCPT + j];
      a00[j] = bb; a01[j] = bb; a10[j] = bb; a11[j] = bb;
    }
    const float* wg = w + (size_t)gu * OCPT * CIN * 9;
    for (int c = 0; c < CIN; c++) {
      const float v00 = lds[(c * IH + qy) * IW + qx];
      const float v01 = lds[(c * IH + qy) * IW + qx + 1];
      const float v10 = lds[(c * IH + qy + 1) * IW + qx];
      const float v11 = lds[(c * IH + qy + 1) * IW + qx + 1];
#pragma unroll
      for (int j = 0; j < OCPT; j++) {
        const float* wc = wg + (size_t)j * CIN * 9 + c * 9;
        // even-y,even-x: ky=1,kx=1
        a00[j] = fmaf(wc[4], v00, a00[j]);
        // even-y,odd-x: kx in {0,2}
        a01[j] = fmaf(wc[3], v00, a01[j]);
        a01[j] = fmaf(wc[5], v01, a01[j]);
        // odd-y,even-x: ky in {0,2}
        a10[j] = fmaf(wc[1], v00, a10[j]);
        a10[j] = fmaf(wc[7], v10, a10[j]);
        // odd-y,odd-x
        a11[j] = fmaf(wc[0], v00, a11[j]);
        a11[j] = fmaf(wc[2], v01, a11[j]);
        a11[j] = fmaf(wc[6], v10, a11[j]);
        a11[j] = fmaf(wc[8], v11, a11[j]);
      }
    }
    const int base = oy * outW + ox;
#pragma unroll
    for (int j = 0; j < OCPT; j++) {
      float* op = out + (size_t)(gu * OCPT + j) * (4 * HWin);
      op[base] = fmaxf(a00[j], 0.f);
      op[base + 1] = fmaxf(a01[j], 0.f);
      op[base + outW] = fmaxf(a10[j], 0.f);
      op[base + outW + 1] = fmaxf(a11[j], 0.f);
    }
  }
}

// ---------------- output conv: 8 -> 1, same pad, no activation -------------
__global__ __launch_bounds__(256) void conv_out_k(
    const float* __restrict__ a, const float* __restrict__ b2,
    const float* __restrict__ w, const float* __restrict__ bias,
    float* __restrict__ out) {
  constexpr int TX = 16, TY = 16, IH = 18, IW = 18, CIN = 8;
  __shared__ float lds[CIN * IH * IW];
  const int x0 = blockIdx.x * TX, y0 = blockIdx.y * TY;
  for (int idx = threadIdx.x; idx < CIN * IH * IW; idx += 256) {
    int c = idx / (IH * IW), r = idx % (IH * IW);
    int yy = r / IW, xx = r % IW;
    int gy = y0 + yy - 1, gx = x0 + xx - 1;
    float v = 0.f;
    if ((unsigned)gy < (unsigned)H0 && (unsigned)gx < (unsigned)W0) {
      int p = c * HW0 + gy * W0 + gx;
      v = a[p] + b2[p];
    }
    lds[(c * IH + yy) * IW + xx] = v;
  }
  __syncthreads();
  const int tx = threadIdx.x % TX, ty = threadIdx.x / TX;
  float acc = bias[0];
  for (int c = 0; c < CIN; c++) {
#pragma unroll
    for (int ky = 0; ky < 3; ky++)
#pragma unroll
      for (int kx = 0; kx < 3; kx++)
        acc = fmaf(lds[(c * IH + ty + ky) * IW + tx + kx], w[c * 9 + ky * 3 + kx], acc);
  }
  out[(y0 + ty) * W0 + x0 + tx] = acc;
}

}  // namespace

extern "C" void kernel_launch(void* const* d_in, const int* in_sizes, int n_in,
                              void* d_out, int out_size, void* d_ws, size_t ws_size,
                              hipStream_t stream) {
  const float* vol = (const float*)d_in[0];
  const float* c1w = (const float*)d_in[1];  const float* c1b = (const float*)d_in[2];
  const float* c2w = (const float*)d_in[3];  const float* c2b = (const float*)d_in[4];
  const float* c3w = (const float*)d_in[5];  const float* c3b = (const float*)d_in[6];
  const float* u3w = (const float*)d_in[7];  const float* u3b = (const float*)d_in[8];
  const float* u2w = (const float*)d_in[9];  const float* u2b = (const float*)d_in[10];
  const float* u1w = (const float*)d_in[11]; const float* u1b = (const float*)d_in[12];
  const float* ow  = (const float*)d_in[13]; const float* ob  = (const float*)d_in[14];
  const float* g1gw = (const float*)d_in[15]; const float* g1gb = (const float*)d_in[16];
  const float* g1cw = (const float*)d_in[17]; const float* g1cb = (const float*)d_in[18];
  const float* g2gw = (const float*)d_in[19]; const float* g2gb = (const float*)d_in[20];
  const float* g2cw = (const float*)d_in[21]; const float* g2cb = (const float*)d_in[22];
  const float* g3gw = (const float*)d_in[23]; const float* g3gb = (const float*)d_in[24];
  const float* g3cw = (const float*)d_in[25]; const float* g3cb = (const float*)d_in[26];
  const float* g4gw = (const float*)d_in[27]; const float* g4gb = (const float*)d_in[28];
  const float* g4cw = (const float*)d_in[29]; const float* g4cb = (const float*)d_in[30];
  float* dout = (float*)d_out;

  float* ws = (float*)d_ws;
  size_t off = 0;
  auto alloc = [&](size_t n) { float* p = ws + off; off += n; return p; };
  // GRU state ping buffers first (contiguous -> single zeroing memset)
  float* s1[2]; float* s2[2]; float* s3[2]; float* s4[2];
  s1[0] = alloc(8 * HW0);  s2[0] = alloc(16 * HW1);
  s3[0] = alloc(32 * HW2); s4[0] = alloc(64 * HW3);
  const size_t pingBytes = off * sizeof(float);
  s1[1] = alloc(8 * HW0);  s2[1] = alloc(16 * HW1);
  s3[1] = alloc(32 * HW2); s4[1] = alloc(64 * HW3);
  float* c1 = alloc(16 * HW1); float* c2 = alloc(32 * HW2); float* c3 = alloc(64 * HW3);
  float* u3 = alloc(32 * HW2); float* u2 = alloc(16 * HW1); float* u1 = alloc(8 * HW0);
  float* gt1 = alloc(16 * HW0); float* gt2 = alloc(32 * HW1);
  float* gt3 = alloc(64 * HW2); float* gt4 = alloc(128 * HW3);
  (void)ws_size; (void)in_sizes; (void)n_in; (void)out_size;

  hipMemsetAsync(d_ws, 0, pingBytes, stream);  // zero initial GRU states

  const int ncs = DEPTH * HW0;  // channel stride inside the volume
  for (int t = 0; t < DEPTH; t++) {
    const float* nc = vol + (size_t)t * HW0;  // depth-t slice (per-channel stride ncs)
    float* s1i = s1[t & 1]; float* s1o = s1[(t + 1) & 1];
    float* s2i = s2[t & 1]; float* s2o = s2[(t + 1) & 1];
    float* s3i = s3[t & 1]; float* s3o = s3[(t + 1) & 1];
    float* s4i = s4[t & 1]; float* s4o = s4[(t + 1) & 1];

    // encoder
    conv_s2_k<8, 16, 16, 16, 4, true><<<dim3(10, 8, 1), 256, 0, stream>>>(
        nc, ncs, H0, W0, c1w, c1b, c1, H1, W1);
    conv_s2_k<16, 32, 16, 8, 4, false><<<dim3(5, 8, 1), 256, 0, stream>>>(
        c1, HW1, H1, W1, c2w, c2b, c2, H2, W2);
    conv_s2_k<32, 64, 8, 8, 4, false><<<dim3(5, 4, 4), 256, 0, stream>>>(
        c2, HW2, H2, W2, c3w, c3b, c3, H3, W3);
    // GRU4 + up3
    conv_gate_k<64, 64, 8, 8, 4, false><<<dim3(5, 4, 8), 256, 0, stream>>>(
        c3, HW3, s4i, H3, W3, g4gw, g4gb, gt4);
    conv_cand_k<64, 64, 8, 8, 4, false><<<dim3(5, 4, 4), 256, 0, stream>>>(
        c3, HW3, s4i, gt4, H3, W3, g4cw, g4cb, s4o);
    convT_k<64, 32, 16, 16, 4, false><<<dim3(5, 4, 2), 256, 0, stream>>>(
        s4o, nullptr, H3, W3, u3w, u3b, u3);
    // GRU3 + up2
    conv_gate_k<32, 32, 8, 8, 4, false><<<dim3(10, 8, 2), 256, 0, stream>>>(
        c2, HW2, s3i, H2, W2, g3gw, g3gb, gt3);
    conv_cand_k<32, 32, 8, 8, 4, false><<<dim3(10, 8, 2), 256, 0, stream>>>(
        c2, HW2, s3i, gt3, H2, W2, g3cw, g3cb, s3o);
    convT_k<32, 16, 16, 16, 4, true><<<dim3(10, 8, 1), 256, 0, stream>>>(
        u3, s3o, H2, W2, u2w, u2b, u2);
    // GRU2 + up1
    conv_gate_k<16, 16, 16, 8, 4, false><<<dim3(10, 16, 2), 256, 0, stream>>>(
        c1, HW1, s2i, H1, W1, g2gw, g2gb, gt2);
    conv_cand_k<16, 16, 16, 8, 4, false><<<dim3(10, 16, 2), 256, 0, stream>>>(
        c1, HW1, s2i, gt2, H1, W1, g2cw, g2cb, s2o);
    convT_k<16, 8, 16, 16, 2, true><<<dim3(20, 16, 1), 256, 0, stream>>>(
        u2, s2o, H1, W1, u1w, u1b, u1);
    // GRU1 + output head
    conv_gate_k<8, 8, 16, 16, 4, true><<<dim3(20, 16, 1), 256, 0, stream>>>(
        nc, ncs, s1i, H0, W0, g1gw, g1gb, gt1);
    conv_cand_k<8, 8, 16, 16, 4, true><<<dim3(20, 16, 1), 256, 0, stream>>>(
        nc, ncs, s1i, gt1, H0, W0, g1cw, g1cb, s1o);
    conv_out_k<<<dim3(20, 16, 1), 256, 0, stream>>>(
        u1, s1o, ow, ob, dout + (size_t)t * HW0);
  }
}

// Round 2
// 9163.810 us; speedup vs baseline: 2.5611x; 2.5611x over previous
//
#include <hip/hip_runtime.h>
#include <math.h>

namespace {

constexpr int H0 = 256, W0 = 320, H1 = 128, W1 = 160, H2 = 64, W2 = 80, H3 = 32, W3 = 40;
constexpr int HW0 = H0 * W0, HW1 = H1 * W1, HW2 = H2 * W2, HW3 = H3 * W3;
constexpr int DEPTH = 48;
constexpr int NCS = DEPTH * HW0;  // channel stride inside the cost volume

// ---------------------------------------------------------------------------
// Generic GRU 3x3 same-pad conv over concat(x, h) (gate) or concat(x, r*h)
// (cand), channel-chunked LDS staging so every level fits in 25.6 KB.
// ---------------------------------------------------------------------------
template <int CX, int CH, int COUT, int TX, int TY, int OCPT, int CHUNK,
          bool NEGX, bool CAND, int ZC>
__device__ __forceinline__ void gru_conv(
    int bx, int by, int zg, int H, int W,
    const float* __restrict__ x, int xcs,
    const float* __restrict__ h, const float* __restrict__ rg,
    const float* __restrict__ w, const float* __restrict__ bias,
    float* __restrict__ out, float* lds) {
  constexpr int CIN = CX + CH, IH = TY + 2, IW = TX + 2;
  constexpr int NPX = TX * TY, SUBS = 256 / NPX, NOCG = COUT / OCPT;
  constexpr int GPER = NOCG / ZC, NITER = GPER / SUBS;
  static_assert(NITER * SUBS == GPER && GPER * ZC == NOCG, "cfg");
  static_assert(CHUNK * IH * IW <= 6400, "lds");
  const int x0 = bx * TX, y0 = by * TY, HW = H * W, tid = threadIdx.x;
  const int px = tid % NPX, sub = tid / NPX, tx = px % TX, ty = px / TX;
  const int gbase = zg * GPER + sub;  // wave-uniform (NPX multiple of 64)
  float acc[NITER][OCPT];
#pragma unroll
  for (int it = 0; it < NITER; it++) {
    const int g = gbase + it * SUBS;
#pragma unroll
    for (int j = 0; j < OCPT; j++) acc[it][j] = bias[g * OCPT + j];
  }
  for (int c0 = 0; c0 < CIN; c0 += CHUNK) {
    __syncthreads();
    for (int idx = tid; idx < CHUNK * IH * IW; idx += 256) {
      int cc = idx / (IH * IW), r = idx % (IH * IW), yy = r / IW, xx = r % IW;
      int gy = y0 + yy - 1, gx = x0 + xx - 1, c = c0 + cc;
      float v = 0.f;
      if ((unsigned)gy < (unsigned)H && (unsigned)gx < (unsigned)W) {
        if (c < CX) {
          v = x[(size_t)c * xcs + gy * W + gx];
          if (NEGX) v = -v;
        } else {
          int p = (c - CX) * HW + gy * W + gx;
          v = h[p];
          if (CAND) v *= rg[p];  // r = first CH channels of gates
        }
      }
      lds[idx] = v;
    }
    __syncthreads();
    for (int c = 0; c < CHUNK; c++) {
      float v[9];
      const float* lp = lds + (c * IH + ty) * IW + tx;
#pragma unroll
      for (int ky = 0; ky < 3; ky++)
#pragma unroll
        for (int kx = 0; kx < 3; kx++) v[ky * 3 + kx] = lp[ky * IW + kx];
#pragma unroll
      for (int it = 0; it < NITER; it++) {
        const int g = __builtin_amdgcn_readfirstlane(gbase + it * SUBS);
        const float* wc = w + ((size_t)(g * OCPT) * CIN + (c0 + c)) * 9;
#pragma unroll
        for (int j = 0; j < OCPT; j++)
#pragma unroll
          for (int k = 0; k < 9; k++)
            acc[it][j] = fmaf(v[k], wc[(size_t)j * CIN * 9 + k], acc[it][j]);
      }
    }
  }
  const int opix = (y0 + ty) * W + x0 + tx;
#pragma unroll
  for (int it = 0; it < NITER; it++) {
    const int g = gbase + it * SUBS;
#pragma unroll
    for (int j = 0; j < OCPT; j++) {
      const int oc = g * OCPT + j;
      float a = acc[it][j];
      if (!CAND) {
        out[oc * HW + opix] = 1.f / (1.f + expf(-a));  // sigmoid gates
      } else {
        float cd = tanhf(a);
        float u = rg[(CH + oc) * HW + opix];  // update gate (2nd half)
        float hv = h[oc * HW + opix];
        out[oc * HW + opix] = u * hv + (1.f - u) * cd;
      }
    }
  }
}

struct GruArgs {
  const float* x; int xcs;
  const float* c1; const float* c2; const float* c3;
  const float* h1; const float* h2; const float* h3; const float* h4;
  const float* g1; const float* g2; const float* g3; const float* g4;
  const float* w1; const float* b1; const float* w2; const float* b2;
  const float* w3; const float* b3; const float* w4; const float* b4;
  float* o1; float* o2; float* o3; float* o4;
};

// One launch: all 4 levels' gate convs. Blocks: L0 320 | L1 320 | L2 160 | L3 160.
__global__ __launch_bounds__(256) void gates_k(GruArgs a) {
  __shared__ float lds[6400];
  const int b = blockIdx.x;
  if (b < 320) {
    gru_conv<8, 8, 16, 16, 16, 8, 16, true, false, 1>(
        b % 20, b / 20, 0, H0, W0, a.x, a.xcs, a.h1, nullptr, a.w1, a.b1, a.o1, lds);
  } else if (b < 640) {
    int l = b - 320;
    gru_conv<16, 16, 32, 16, 8, 8, 32, false, false, 2>(
        l % 10, (l / 10) % 16, l / 160, H1, W1, a.c1, HW1, a.h2, nullptr, a.w2, a.b2, a.o2, lds);
  } else if (b < 800) {
    int l = b - 640;
    gru_conv<32, 32, 64, 8, 8, 8, 64, false, false, 2>(
        l % 10, (l / 10) % 8, l / 80, H2, W2, a.c2, HW2, a.h3, nullptr, a.w3, a.b3, a.o3, lds);
  } else {
    int l = b - 800;
    gru_conv<64, 64, 128, 8, 8, 4, 64, false, false, 8>(
        l % 5, (l / 5) % 4, l / 20, H3, W3, a.c3, HW3, a.h4, nullptr, a.w4, a.b4, a.o4, lds);
  }
}

// One launch: all 4 levels' cand convs + GRU combine. Blocks: 320|160|80|80.
__global__ __launch_bounds__(256) void cands_k(GruArgs a) {
  __shared__ float lds[6400];
  const int b = blockIdx.x;
  if (b < 320) {
    gru_conv<8, 8, 8, 16, 16, 8, 16, true, true, 1>(
        b % 20, b / 20, 0, H0, W0, a.x, a.xcs, a.h1, a.g1, a.w1, a.b1, a.o1, lds);
  } else if (b < 480) {
    int l = b - 320;
    gru_conv<16, 16, 16, 16, 8, 8, 32, false, true, 1>(
        l % 10, l / 10, 0, H1, W1, a.c1, HW1, a.h2, a.g2, a.w2, a.b2, a.o2, lds);
  } else if (b < 560) {
    int l = b - 480;
    gru_conv<32, 32, 32, 8, 8, 8, 64, false, true, 1>(
        l % 10, l / 10, 0, H2, W2, a.c2, HW2, a.h3, a.g3, a.w3, a.b3, a.o3, lds);
  } else {
    int l = b - 560;
    gru_conv<64, 64, 64, 8, 8, 4, 64, false, true, 4>(
        l % 5, (l / 5) % 4, l / 20, H3, W3, a.c3, HW3, a.h4, a.g4, a.w4, a.b4, a.o4, lds);
  }
}

// ---------------- stride-2 3x3 conv + ReLU, t-batched ----------------------
template <int CIN, int COUT, int TX, int TY, int OCPT, int ZC, bool NEG>
__global__ __launch_bounds__(256) void enc_k(
    const float* __restrict__ in, int inCS, size_t inTS, int inSlots,
    const float* __restrict__ w, const float* __restrict__ bias,
    float* __restrict__ out, size_t outTS, int outSlots,
    int inH, int inW, int outH, int outW, int t0) {
  constexpr int IH = 2 * TY + 1, IW = 2 * TX + 1;
  constexpr int NPX = TX * TY, SUBS = 256 / NPX, NOCG = COUT / OCPT;
  constexpr int GPER = NOCG / ZC, NITER = GPER / SUBS;
  static_assert(NITER * SUBS == GPER, "cfg");
  __shared__ float lds[CIN * IH * IW];
  const int z = blockIdx.z, tt = t0 + z / ZC, zg = z % ZC;
  const float* inp = in + (size_t)(tt % inSlots) * inTS;
  float* outp = out + (size_t)(tt % outSlots) * outTS;
  const int x0 = blockIdx.x * TX, y0 = blockIdx.y * TY;
  const int ix0 = 2 * x0 - 1, iy0 = 2 * y0 - 1, tid = threadIdx.x;
  for (int idx = tid; idx < CIN * IH * IW; idx += 256) {
    int c = idx / (IH * IW), r = idx % (IH * IW), yy = r / IW, xx = r % IW;
    int gy = iy0 + yy, gx = ix0 + xx;
    float v = 0.f;
    if ((unsigned)gy < (unsigned)inH && (unsigned)gx < (unsigned)inW)
      v = inp[(size_t)c * inCS + gy * inW + gx];
    lds[idx] = NEG ? -v : v;
  }
  __syncthreads();
  const int px = tid % NPX, sub = tid / NPX, tx = px % TX, ty = px / TX;
  const int gbase = zg * GPER + sub;
  float acc[NITER][OCPT];
#pragma unroll
  for (int it = 0; it < NITER; it++) {
    const int g = gbase + it * SUBS;
#pragma unroll
    for (int j = 0; j < OCPT; j++) acc[it][j] = bias[g * OCPT + j];
  }
  for (int c = 0; c < CIN; c++) {
    float v[9];
    const float* lp = lds + (c * IH + 2 * ty) * IW + 2 * tx;
#pragma unroll
    for (int ky = 0; ky < 3; ky++)
#pragma unroll
      for (int kx = 0; kx < 3; kx++) v[ky * 3 + kx] = lp[ky * IW + kx];
#pragma unroll
    for (int it = 0; it < NITER; it++) {
      const int g = __builtin_amdgcn_readfirstlane(gbase + it * SUBS);
      const float* wc = w + ((size_t)(g * OCPT) * CIN + c) * 9;
#pragma unroll
      for (int j = 0; j < OCPT; j++)
#pragma unroll
        for (int k = 0; k < 9; k++)
          acc[it][j] = fmaf(v[k], wc[(size_t)j * CIN * 9 + k], acc[it][j]);
    }
  }
  const int ox = x0 + tx, oy = y0 + ty;
#pragma unroll
  for (int it = 0; it < NITER; it++) {
    const int g = gbase + it * SUBS;
#pragma unroll
    for (int j = 0; j < OCPT; j++)
      outp[((size_t)(g * OCPT + j) * outH + oy) * outW + ox] = fmaxf(acc[it][j], 0.f);
  }
}

// ------- ConvTranspose 3x3 s2 p1 op1 + ReLU, t-batched, quad scheme --------
template <int CIN, int COUT, int OCPT, int ZC, bool SUM2>
__global__ __launch_bounds__(256) void convT_b_k(
    const float* __restrict__ inA, size_t aTS, int aSlots,
    const float* __restrict__ inB, size_t bTS, int bSlots,
    const float* __restrict__ w, const float* __restrict__ bias,
    float* __restrict__ out, size_t oTS, int oSlots,
    int inH, int inW, int t0) {
  __shared__ float lds[CIN * 81];  // 9x9 input patch for a 16x16 output tile
  const int z = blockIdx.z, tt = t0 + z / ZC, zg = z % ZC;
  const float* A = inA + (size_t)(tt % aSlots) * aTS;
  const float* Bp = inB + (size_t)(tt % bSlots) * bTS;
  float* outp = out + (size_t)(tt % oSlots) * oTS;
  const int x0 = blockIdx.x * 16, y0 = blockIdx.y * 16, ix0 = x0 / 2, iy0 = y0 / 2;
  const int HWin = inH * inW, tid = threadIdx.x;
  for (int idx = tid; idx < CIN * 81; idx += 256) {
    int c = idx / 81, r = idx % 81, yy = r / 9, xx = r % 9;
    int gy = iy0 + yy, gx = ix0 + xx;
    float v = 0.f;
    if (gy < inH && gx < inW) {
      int p = c * HWin + gy * inW + gx;
      v = A[p];
      if (SUM2) v += Bp[p];
    }
    lds[idx] = v;
  }
  __syncthreads();
  constexpr int NOCG = COUT / OCPT, GPER = NOCG / ZC, SUBS = 4, NITER = GPER / SUBS;
  static_assert(NITER * SUBS == GPER, "cfg");
  const int q = tid % 64, sub = tid / 64, qx = q % 8, qy = q / 8;
  const int outW = 2 * inW, oy = y0 + 2 * qy, ox = x0 + 2 * qx;
  const int gbase = zg * GPER + sub;
  float a00[NITER][OCPT], a01[NITER][OCPT], a10[NITER][OCPT], a11[NITER][OCPT];
#pragma unroll
  for (int it = 0; it < NITER; it++) {
    const int g = gbase + it * SUBS;
#pragma unroll
    for (int j = 0; j < OCPT; j++) {
      float bb = bias[g * OCPT + j];
      a00[it][j] = bb; a01[it][j] = bb; a10[it][j] = bb; a11[it][j] = bb;
    }
  }
  for (int c = 0; c < CIN; c++) {
    const float* ip = lds + c * 81 + qy * 9 + qx;
    const float v00 = ip[0], v01 = ip[1], v10 = ip[9], v11 = ip[10];
#pragma unroll
    for (int it = 0; it < NITER; it++) {
      const int g = __builtin_amdgcn_readfirstlane(gbase + it * SUBS);
      const float* wg = w + ((size_t)(g * OCPT) * CIN + c) * 9;
#pragma unroll
      for (int j = 0; j < OCPT; j++) {
        const float* wc = wg + (size_t)j * CIN * 9;
        a00[it][j] = fmaf(wc[4], v00, a00[it][j]);
        a01[it][j] = fmaf(wc[3], v00, a01[it][j]);
        a01[it][j] = fmaf(wc[5], v01, a01[it][j]);
        a10[it][j] = fmaf(wc[1], v00, a10[it][j]);
        a10[it][j] = fmaf(wc[7], v10, a10[it][j]);
        a11[it][j] = fmaf(wc[0], v00, a11[it][j]);
        a11[it][j] = fmaf(wc[2], v01, a11[it][j]);
        a11[it][j] = fmaf(wc[6], v10, a11[it][j]);
        a11[it][j] = fmaf(wc[8], v11, a11[it][j]);
      }
    }
  }
  const int base = oy * outW + ox;
#pragma unroll
  for (int it = 0; it < NITER; it++) {
    const int g = gbase + it * SUBS;
#pragma unroll
    for (int j = 0; j < OCPT; j++) {
      float* op = outp + (size_t)(g * OCPT + j) * (4 * HWin);
      op[base] = fmaxf(a00[it][j], 0.f);
      op[base + 1] = fmaxf(a01[it][j], 0.f);
      op[base + outW] = fmaxf(a10[it][j], 0.f);
      op[base + outW + 1] = fmaxf(a11[it][j], 0.f);
    }
  }
}

// ------- fused: u1 = relu(convT(u2 + r2)); reg = conv3x3(u1 + r1) ----------
__global__ __launch_bounds__(256) void up1out_k(
    const float* __restrict__ u2, size_t u2TS, int u2S,
    const float* __restrict__ r2, size_t r2TS, int r2S,
    const float* __restrict__ r1, size_t r1TS, int r1S,
    const float* __restrict__ wT, const float* __restrict__ bT,
    const float* __restrict__ wo, const float* __restrict__ bo,
    float* __restrict__ dout, int t0) {
  __shared__ float ins[16 * 121];  // (u2+r2) patch 11x11 x16ch
  __shared__ float u1h[8 * 400];   // u1 halo tile 20x20 x8ch (even origin)
  const int t = t0 + blockIdx.z;
  const float* U = u2 + (size_t)(t % u2S) * u2TS;
  const float* R2 = r2 + (size_t)(t % r2S) * r2TS;
  const float* R1 = r1 + (size_t)(t % r1S) * r1TS;
  const int x0 = blockIdx.x * 16, y0 = blockIdx.y * 16;
  const int ix0 = x0 / 2 - 1, iy0 = y0 / 2 - 1, tid = threadIdx.x;
  for (int idx = tid; idx < 16 * 121; idx += 256) {
    int c = idx / 121, r = idx % 121, yy = r / 11, xx = r % 11;
    int gy = iy0 + yy, gx = ix0 + xx;
    float v = 0.f;
    if ((unsigned)gy < (unsigned)H1 && (unsigned)gx < (unsigned)W1) {
      int p = c * HW1 + gy * W1 + gx;
      v = U[p] + R2[p];
    }
    ins[idx] = v;
  }
  __syncthreads();
  for (int u = tid; u < 800; u += 256) {  // 8 ch x 100 quads
    int ch = u / 100, qq = u % 100, qy = qq / 10, qx = qq % 10;
    float bb = bT[ch];
    float a00 = bb, a01 = bb, a10 = bb, a11 = bb;
    const float* wb = wT + (size_t)ch * 16 * 9;
    for (int ic = 0; ic < 16; ic++) {
      const float* wc = wb + ic * 9;
      const float* ip = ins + ic * 121 + qy * 11 + qx;
      float v00 = ip[0], v01 = ip[1], v10 = ip[11], v11 = ip[12];
      a00 = fmaf(wc[4], v00, a00);
      a01 = fmaf(wc[3], v00, a01); a01 = fmaf(wc[5], v01, a01);
      a10 = fmaf(wc[1], v00, a10); a10 = fmaf(wc[7], v10, a10);
      a11 = fmaf(wc[0], v00, a11); a11 = fmaf(wc[2], v01, a11);
      a11 = fmaf(wc[6], v10, a11); a11 = fmaf(wc[8], v11, a11);
    }
    float* up = u1h + ch * 400 + (2 * qy) * 20 + 2 * qx;
    up[0] = fmaxf(a00, 0.f);  up[1] = fmaxf(a01, 0.f);
    up[20] = fmaxf(a10, 0.f); up[21] = fmaxf(a11, 0.f);
  }
  __syncthreads();
  for (int idx = tid; idx < 8 * 400; idx += 256) {  // += r1 ; zero OOB halo
    int c = idx / 400, r = idx % 400, hy = r / 20, hx = r % 20;
    int gy = y0 - 2 + hy, gx = x0 - 2 + hx;
    if ((unsigned)gy < (unsigned)H0 && (unsigned)gx < (unsigned)W0)
      u1h[idx] += R1[c * HW0 + gy * W0 + gx];
    else
      u1h[idx] = 0.f;
  }
  __syncthreads();
  const int tx = tid % 16, ty = tid / 16;
  float acc = bo[0];
  for (int c = 0; c < 8; c++) {
    const float* up = u1h + c * 400 + (ty + 1) * 20 + tx + 1;
#pragma unroll
    for (int ky = 0; ky < 3; ky++)
#pragma unroll
      for (int kx = 0; kx < 3; kx++)
        acc = fmaf(up[ky * 20 + kx], wo[c * 9 + ky * 3 + kx], acc);
  }
  dout[(size_t)t * HW0 + (y0 + ty) * W0 + x0 + tx] = acc;
}

}  // namespace

extern "C" void kernel_launch(void* const* d_in, const int* in_sizes, int n_in,
                              void* d_out, int out_size, void* d_ws, size_t ws_size,
                              hipStream_t stream) {
  const float* vol = (const float*)d_in[0];
  const float* c1w = (const float*)d_in[1];  const float* c1b = (const float*)d_in[2];
  const float* c2w = (const float*)d_in[3];  const float* c2b = (const float*)d_in[4];
  const float* c3w = (const float*)d_in[5];  const float* c3b = (const float*)d_in[6];
  const float* u3w = (const float*)d_in[7];  const float* u3b = (const float*)d_in[8];
  const float* u2w = (const float*)d_in[9];  const float* u2b = (const float*)d_in[10];
  const float* u1w = (const float*)d_in[11]; const float* u1b = (const float*)d_in[12];
  const float* ow  = (const float*)d_in[13]; const float* ob  = (const float*)d_in[14];
  const float* g1gw = (const float*)d_in[15]; const float* g1gb = (const float*)d_in[16];
  const float* g1cw = (const float*)d_in[17]; const float* g1cb = (const float*)d_in[18];
  const float* g2gw = (const float*)d_in[19]; const float* g2gb = (const float*)d_in[20];
  const float* g2cw = (const float*)d_in[21]; const float* g2cb = (const float*)d_in[22];
  const float* g3gw = (const float*)d_in[23]; const float* g3gb = (const float*)d_in[24];
  const float* g3cw = (const float*)d_in[25]; const float* g3cb = (const float*)d_in[26];
  const float* g4gw = (const float*)d_in[27]; const float* g4gb = (const float*)d_in[28];
  const float* g4cw = (const float*)d_in[29]; const float* g4cb = (const float*)d_in[30];
  float* dout = (float*)d_out;
  (void)in_sizes; (void)n_in; (void)out_size;

  // per-t element counts
  const size_t r1Sz = 8 * HW0, r2Sz = 16 * HW1, r3Sz = 32 * HW2, r4Sz = 64 * HW3;
  const size_t c1Sz = 16 * HW1, c2Sz = 32 * HW2, c3Sz = 64 * HW3;
  const size_t g1Sz = 16 * HW0, g2Sz = 32 * HW1, g3Sz = 64 * HW2, g4Sz = 128 * HW3;
  const size_t ZB = 8 * HW0;
  const size_t rTot = r1Sz + r2Sz + r3Sz + r4Sz;
  const size_t cTot = c1Sz + c2Sz + c3Sz;
  const size_t gTot = g1Sz + g2Sz + g3Sz + g4Sz;
  const size_t uTot = 32 * HW2 + 16 * HW1;
  // tier A: 48-deep r+c storage, decoder u-buffers aliased onto c region.
  const size_t needA = (ZB + 48 * rTot + 48 * cTot + gTot) * sizeof(float);
  const size_t needB = (ZB + 2 * rTot + 48 * cTot + gTot + uTot) * sizeof(float);
  const int tier = ws_size >= needA ? 0 : (ws_size >= needB ? 1 : 2);
  const int TR = (tier == 0) ? 48 : 2;   // r-state slots
  const int TC = (tier == 2) ? 1 : 48;   // encoder-feature slots

  float* ws = (float*)d_ws;
  size_t off = 0;
  auto alloc = [&](size_t n) { float* p = ws + off; off += n; return p; };
  float* zb = alloc(ZB);
  float* r1 = alloc((size_t)TR * r1Sz); float* r2 = alloc((size_t)TR * r2Sz);
  float* r3 = alloc((size_t)TR * r3Sz); float* r4 = alloc((size_t)TR * r4Sz);
  float* g1 = alloc(g1Sz); float* g2 = alloc(g2Sz);
  float* g3 = alloc(g3Sz); float* g4 = alloc(g4Sz);
  float* c1a = alloc((size_t)TC * c1Sz);
  float* c2a = alloc((size_t)TC * c2Sz);
  float* c3a = alloc((size_t)TC * c3Sz);
  float *u3a, *u2a;
  if (tier == 0) {  // decoder runs after the scan; c region is dead by then
    u3a = c1a;
    u2a = c1a + 48 * (32 * HW2);
  } else {
    u3a = alloc(32 * HW2);
    u2a = alloc(16 * HW1);
  }

  hipMemsetAsync(zb, 0, ZB * sizeof(float), stream);  // t=0 GRU states

  const int TD = (tier == 0) ? 48 : 1;  // decoder batch
  if (tier < 2) {  // batched encoder, all 48 depths
    enc_k<8, 16, 16, 16, 8, 1, true><<<dim3(10, 8, 48), 256, 0, stream>>>(
        vol, NCS, (size_t)HW0, 48, c1w, c1b, c1a, c1Sz, 48, H0, W0, H1, W1, 0);
    enc_k<16, 32, 16, 8, 8, 1, false><<<dim3(5, 8, 48), 256, 0, stream>>>(
        c1a, HW1, c1Sz, 48, c2w, c2b, c2a, c2Sz, 48, H1, W1, H2, W2, 0);
    enc_k<32, 64, 8, 8, 8, 2, false><<<dim3(5, 4, 96), 256, 0, stream>>>(
        c2a, HW2, c2Sz, 48, c3w, c3b, c3a, c3Sz, 48, H2, W2, H3, W3, 0);
  }

  for (int t = 0; t < DEPTH; t++) {
    if (tier == 2) {
      enc_k<8, 16, 16, 16, 8, 1, true><<<dim3(10, 8, 1), 256, 0, stream>>>(
          vol, NCS, (size_t)HW0, 48, c1w, c1b, c1a, c1Sz, 1, H0, W0, H1, W1, t);
      enc_k<16, 32, 16, 8, 8, 1, false><<<dim3(5, 8, 1), 256, 0, stream>>>(
          c1a, HW1, c1Sz, 1, c2w, c2b, c2a, c2Sz, 1, H1, W1, H2, W2, t);
      enc_k<32, 64, 8, 8, 8, 2, false><<<dim3(5, 4, 2), 256, 0, stream>>>(
          c2a, HW2, c2Sz, 1, c3w, c3b, c3a, c3Sz, 1, H2, W2, H3, W3, t);
    }
    const float* x0p = vol + (size_t)t * HW0;
    const float* h1p = t ? r1 + (size_t)((t - 1) % TR) * r1Sz : zb;
    const float* h2p = t ? r2 + (size_t)((t - 1) % TR) * r2Sz : zb;
    const float* h3p = t ? r3 + (size_t)((t - 1) % TR) * r3Sz : zb;
    const float* h4p = t ? r4 + (size_t)((t - 1) % TR) * r4Sz : zb;
    const float* c1p = c1a + (size_t)(t % TC) * c1Sz;
    const float* c2p = c2a + (size_t)(t % TC) * c2Sz;
    const float* c3p = c3a + (size_t)(t % TC) * c3Sz;
    float* o1p = r1 + (size_t)(t % TR) * r1Sz;
    float* o2p = r2 + (size_t)(t % TR) * r2Sz;
    float* o3p = r3 + (size_t)(t % TR) * r3Sz;
    float* o4p = r4 + (size_t)(t % TR) * r4Sz;

    GruArgs ga{x0p, NCS, c1p, c2p, c3p, h1p, h2p, h3p, h4p,
               nullptr, nullptr, nullptr, nullptr,
               g1gw, g1gb, g2gw, g2gb, g3gw, g3gb, g4gw, g4gb,
               g1, g2, g3, g4};
    gates_k<<<dim3(960), 256, 0, stream>>>(ga);
    GruArgs ca{x0p, NCS, c1p, c2p, c3p, h1p, h2p, h3p, h4p,
               g1, g2, g3, g4,
               g1cw, g1cb, g2cw, g2cb, g3cw, g3cb, g4cw, g4cb,
               o1p, o2p, o3p, o4p};
    cands_k<<<dim3(640), 256, 0, stream>>>(ca);

    if (tier > 0) {  // per-t decoder
      convT_b_k<64, 32, 4, 2, false><<<dim3(5, 4, 2), 256, 0, stream>>>(
          r4, r4Sz, TR, r4, 0, 1, u3w, u3b, u3a, (size_t)32 * HW2, 1, H3, W3, t);
      convT_b_k<32, 16, 4, 1, true><<<dim3(10, 8, 1), 256, 0, stream>>>(
          u3a, (size_t)32 * HW2, 1, r3, r3Sz, TR, u2w, u2b, u2a, (size_t)16 * HW1, 1,
          H2, W2, t);
      up1out_k<<<dim3(20, 16, 1), 256, 0, stream>>>(
          u2a, (size_t)16 * HW1, 1, r2, r2Sz, TR, r1, r1Sz, TR,
          u1w, u1b, ow, ob, dout, t);
    }
  }

  if (tier == 0) {  // batched decoder over all 48 depths
    convT_b_k<64, 32, 4, 2, false><<<dim3(5, 4, 2 * TD), 256, 0, stream>>>(
        r4, r4Sz, 48, r4, 0, 1, u3w, u3b, u3a, (size_t)32 * HW2, 48, H3, W3, 0);
    convT_b_k<32, 16, 4, 1, true><<<dim3(10, 8, TD), 256, 0, stream>>>(
        u3a, (size_t)32 * HW2, 48, r3, r3Sz, 48, u2w, u2b, u2a, (size_t)16 * HW1, 48,
        H2, W2, 0);
    up1out_k<<<dim3(20, 16, TD), 256, 0, stream>>>(
        u2a, (size_t)16 * HW1, 48, r2, r2Sz, 48, r1, r1Sz, 48,
        u1w, u1b, ow, ob, dout, 0);
  }
}